// Round 8
// baseline (262.291 us; speedup 1.0000x reference)
//
#include <hip/hip_runtime.h>
#include <stdint.h>

#define M_DIM 8192
#define N_DIM 4096
#define K_DIM 4096
#define NT (K_DIM / 128)  // 32 k-tiles of 128 fp8 bytes

typedef float f32x4 __attribute__((ext_vector_type(4)));
typedef int v4i __attribute__((ext_vector_type(4)));
typedef int v8i __attribute__((ext_vector_type(8)));
typedef uint32_t u32;

// ---------- helpers ----------

__device__ __forceinline__ void gload_lds16(const void* g, void* l) {
  __builtin_amdgcn_global_load_lds(
      (__attribute__((address_space(1))) void*)(g),
      (__attribute__((address_space(3))) void*)(l), 16, 0, 0);
}

__device__ __forceinline__ float clipdiv(float v, float s) {
  v = v / s;
  return fminf(fmaxf(v, -448.f), 448.f);
}

__device__ __forceinline__ u32 pack4_fp8(float a, float b, float c, float d) {
  int w = __builtin_amdgcn_cvt_pk_fp8_f32(a, b, 0, false);
  w = __builtin_amdgcn_cvt_pk_fp8_f32(c, d, w, true);
  return (u32)w;
}

__device__ __forceinline__ v8i rd8(const void* lo, const void* hi) {
  v4i l = *(const v4i*)lo;
  v4i h = *(const v4i*)hi;
  return __builtin_shufflevector(l, h, 0, 1, 2, 3, 4, 5, 6, 7);
}

__device__ __forceinline__ f32x4 mfma8(v8i a, v8i b, f32x4 c) {
  return __builtin_amdgcn_mfma_scale_f32_16x16x128_f8f6f4(
      a, b, c, 0, 0, 0, 0x7f7f7f7f, 0, 0x7f7f7f7f);
}

// ---------- quantize A (row-major M x K, f32 -> e4m3fn) ----------

__global__ __launch_bounds__(256) void quant_a(const float* __restrict__ x,
                                               u32* __restrict__ q,
                                               const float* __restrict__ scale,
                                               int nv4) {
  int base = blockIdx.x * 1024 + threadIdx.x;
  float s = scale[0];
#pragma unroll
  for (int r = 0; r < 4; ++r) {
    int idx = base + r * 256;
    if (idx < nv4) {
      float4 v = ((const float4*)x)[idx];
      q[idx] = pack4_fp8(clipdiv(v.x, s), clipdiv(v.y, s),
                         clipdiv(v.z, s), clipdiv(v.w, s));
    }
  }
}

// ---------- quantize + transpose B (K x N f32 -> N x K fp8), u32-packed ----

__global__ __launch_bounds__(256) void quant_b_t(const float* __restrict__ B,
                                                 uint8_t* __restrict__ qT,
                                                 const float* __restrict__ scale) {
  __shared__ u32 lt[64 * 17];  // 64 n-rows x 16 dwords + 1 pad
  int tid = threadIdx.x;
  int kt = blockIdx.x * 64;
  int nt = blockIdx.y * 64;
  float s = scale[0];

  int kq = tid >> 4;  // 0..15 -> k0 = 4*kq
  int nq = tid & 15;  // 0..15 -> n0 = 4*nq
  int k0 = kq * 4, n0 = nq * 4;
  const float* src = B + (long)(kt + k0) * N_DIM + nt + n0;
  float4 v0 = *(const float4*)(src);
  float4 v1 = *(const float4*)(src + N_DIM);
  float4 v2 = *(const float4*)(src + 2 * N_DIM);
  float4 v3 = *(const float4*)(src + 3 * N_DIM);

  lt[(n0 + 0) * 17 + kq] = pack4_fp8(clipdiv(v0.x, s), clipdiv(v1.x, s),
                                     clipdiv(v2.x, s), clipdiv(v3.x, s));
  lt[(n0 + 1) * 17 + kq] = pack4_fp8(clipdiv(v0.y, s), clipdiv(v1.y, s),
                                     clipdiv(v2.y, s), clipdiv(v3.y, s));
  lt[(n0 + 2) * 17 + kq] = pack4_fp8(clipdiv(v0.z, s), clipdiv(v1.z, s),
                                     clipdiv(v2.z, s), clipdiv(v3.z, s));
  lt[(n0 + 3) * 17 + kq] = pack4_fp8(clipdiv(v0.w, s), clipdiv(v1.w, s),
                                     clipdiv(v2.w, s), clipdiv(v3.w, s));
  __syncthreads();

  int n = tid >> 2, ch = tid & 3;
  uint4 o;
  o.x = lt[n * 17 + ch * 4 + 0];
  o.y = lt[n * 17 + ch * 4 + 1];
  o.z = lt[n * 17 + ch * 4 + 2];
  o.w = lt[n * 17 + ch * 4 + 3];
  *(uint4*)&qT[(long)(nt + n) * K_DIM + kt + ch * 16] = o;
}

// ---------- 256x256 MX-fp8 GEMM: A via LDS, B direct global->register ----
// Round-7 schedule, minus B staging. 8 waves (2M x 4N), wave tile 128x64.
// Per K-tile per wave: 16 ds_read_b128 (A only), 8 global_load_dwordx4
// (B-frags: lane reads 32 contiguous bytes of BqT row rb), 32 MFMA.
// LDS demand per CU per tile drops 192->128 reads + half the stage writes:
// MFMA pipe (~2209 cy) becomes the binding resource instead of LDS (~3800).
// B duplication: each B byte loaded by 2 waves (wr=0/1) -> L1/L2 absorbs.
// Schedule per K-tile: load B(t) regs, stage A(t+1)->buf^1, ds_read A(t),
// MFMA (compiler inserts vmcnt before first B use, lgkmcnt before A use),
// vmcnt(0), s_barrier. WAR: buf^1 untouched by readers this phase; reads of
// buf retire before each wave's MFMAs hence before the barrier. RAW: drain.

template <int BUF>
__device__ __forceinline__ void stage_a(const uint8_t* const (&gA)[4],
                                        uint8_t* lds, const int (&ldo)[4],
                                        long ko) {
#pragma unroll
  for (int r = 0; r < 4; ++r)
    gload_lds16(gA[r] + ko, lds + BUF * 32768 + ldo[r]);
}

__device__ __forceinline__ void load_b(v8i (&b)[4],
                                       const uint8_t* const (&pB)[4], long ko) {
#pragma unroll
  for (int j = 0; j < 4; ++j) b[j] = rd8(pB[j] + ko, pB[j] + ko + 16);
}

template <int BUF>
__device__ __forceinline__ void compute_tile(const uint8_t* lds,
                                             const int (&offA)[8][2],
                                             const v8i (&b)[4],
                                             f32x4 (&acc)[8][4]) {
  const uint8_t* Ab = lds + BUF * 32768;
#pragma unroll
  for (int h = 0; h < 2; ++h) {
    v8i a[4];
#pragma unroll
    for (int i = 0; i < 4; ++i)
      a[i] = rd8(Ab + offA[h * 4 + i][0], Ab + offA[h * 4 + i][1]);
#pragma unroll
    for (int i = 0; i < 4; ++i)
#pragma unroll
      for (int j = 0; j < 4; ++j)
        acc[h * 4 + i][j] = mfma8(a[i], b[j], acc[h * 4 + i][j]);
  }
}

__global__ __launch_bounds__(512, 2) void gemm_mx(const uint8_t* __restrict__ Aq,
                                                  const uint8_t* __restrict__ BqT,
                                                  float* __restrict__ C,
                                                  const float* __restrict__ sA,
                                                  const float* __restrict__ sB) {
  __shared__ __align__(16) uint8_t lds[65536];  // A only: 2 bufs x 32 KB

  const int tid = threadIdx.x;
  const int lane = tid & 63;
  const int wid = tid >> 6;
  const int wr = wid >> 2;  // 0..1: 128-row strip of A
  const int wc = wid & 3;   // 0..3: 64-col strip of B
  const int r16 = lane & 15;
  const int hi = lane >> 4;

  // XCD-aware swizzle: 512 wgs, 64 per XCD chunk (bijective, 512%8==0)
  int bid = blockIdx.x;
  int wg = (bid & 7) * 64 + (bid >> 3);
  const long bm = (long)(wg >> 4) * 256;  // 32 M-tiles
  const long bn = (long)(wg & 15) * 256;  // 16 N-tiles

  // scales: materialize before staging so their loads never sit in the vmem
  // queue during the counted waits.
  float s = sA[0] * sB[0];
  asm volatile("" ::"v"(s));

  // --- A staging: 2048 granules, 4 per thread, pre-swizzled source ---
  const uint8_t* gA[4];
  int ldo[4];
#pragma unroll
  for (int r = 0; r < 4; ++r) {
    int gid = tid + 512 * r;
    int row = gid >> 3, gc = gid & 7;
    int sc = (gc ^ (row & 7)) << 4;  // pre-swizzled source granule
    gA[r] = Aq + (bm + row) * (long)K_DIM + sc;
    ldo[r] = gid * 16;  // linear LDS dest
  }

  // --- A fragment read offsets (loop-invariant, swizzled) ---
  int offA[8][2];
#pragma unroll
  for (int mi = 0; mi < 8; ++mi) {
    int ra = wr * 128 + mi * 16 + r16;  // 0..255
#pragma unroll
    for (int g = 0; g < 2; ++g) {
      int lg = 2 * hi + g;
      offA[mi][g] = ra * 128 + ((lg ^ (ra & 7)) << 4);
    }
  }

  // --- B fragment global base pointers (per lane, 32 contiguous bytes) ---
  const uint8_t* pB[4];
#pragma unroll
  for (int nj = 0; nj < 4; ++nj) {
    long rb = bn + wc * 64 + nj * 16 + r16;
    pB[nj] = BqT + rb * (long)K_DIM + hi * 32;
  }

  f32x4 acc[8][4] = {};

  // ---- prologue ----
  stage_a<0>(gA, lds, ldo, 0);
  asm volatile("s_waitcnt vmcnt(0)" ::: "memory");
  __builtin_amdgcn_s_barrier();

  // ---- main loop: 2 K-tiles per iteration, static buffer indices ----
  for (int i = 0; i < NT / 2; ++i) {
    {
      long kt0 = (long)(2 * i) * 128;
      long kt1 = (long)((2 * i + 1) & (NT - 1)) * 128;
      v8i b[4];
      load_b(b, pB, kt0);          // 8 global_load_dwordx4 (oldest in queue)
      stage_a<1>(gA, lds, ldo, kt1);  // 4 gload_lds for t+1
      compute_tile<0>(lds, offA, b, acc);
      asm volatile("s_waitcnt vmcnt(0)" ::: "memory");
      __builtin_amdgcn_s_barrier();
    }
    {
      long kt1 = (long)(2 * i + 1) * 128;
      long kt2 = (long)((2 * i + 2) & (NT - 1)) * 128;  // wraps harmlessly
      v8i b[4];
      load_b(b, pB, kt1);
      stage_a<0>(gA, lds, ldo, kt2);
      compute_tile<1>(lds, offA, b, acc);
      asm volatile("s_waitcnt vmcnt(0)" ::: "memory");
      __builtin_amdgcn_s_barrier();
    }
  }

  // ---- epilogue: C-write ----
#pragma unroll
  for (int mi = 0; mi < 8; ++mi)
#pragma unroll
    for (int nj = 0; nj < 4; ++nj) {
      long row = bm + wr * 128 + mi * 16 + hi * 4;  // C/D: row=(lane>>4)*4+q
      long col = bn + wc * 64 + nj * 16 + r16;      //      col=lane&15
      float* cp = C + row * N_DIM + col;
      f32x4 v = acc[mi][nj];
#pragma unroll
      for (int q = 0; q < 4; ++q) cp[(long)q * N_DIM] = v[q] * s;
    }
}

// ---------- launcher ----------

extern "C" void kernel_launch(void* const* d_in, const int* in_sizes, int n_in,
                              void* d_out, int out_size, void* d_ws, size_t ws_size,
                              hipStream_t stream) {
  const float* A = (const float*)d_in[0];   // (8192, 4096)
  const float* B = (const float*)d_in[1];   // (4096, 4096)
  const float* sA = (const float*)d_in[2];  // input_scale
  const float* sB = (const float*)d_in[4];  // kernel_scale
  float* out = (float*)d_out;

  uint8_t* Aq = (uint8_t*)d_ws;               // M*K fp8
  uint8_t* BqT = Aq + (size_t)M_DIM * K_DIM;  // N*K fp8 (transposed)

  int nv4_a = M_DIM * K_DIM / 4;
  quant_a<<<nv4_a / 1024, 256, 0, stream>>>(A, (u32*)Aq, sA, nv4_a);
  quant_b_t<<<dim3(K_DIM / 64, N_DIM / 64), 256, 0, stream>>>(B, BqT, sB);
  gemm_mx<<<dim3((M_DIM / 256) * (N_DIM / 256)), 512, 0, stream>>>(Aq, BqT, out, sA, sB);
}

// Round 9
// 189.130 us; speedup vs baseline: 1.3868x; 1.3868x over previous
//
#include <hip/hip_runtime.h>
#include <stdint.h>

#define M_DIM 8192
#define N_DIM 4096
#define K_DIM 4096
#define NT (K_DIM / 128)  // 32 k-tiles of 128 fp8 bytes

typedef float f32x4 __attribute__((ext_vector_type(4)));
typedef float f32x16 __attribute__((ext_vector_type(16)));
typedef int v4i __attribute__((ext_vector_type(4)));
typedef int v8i __attribute__((ext_vector_type(8)));
typedef uint32_t u32;

// ---------- helpers ----------

__device__ __forceinline__ void gload_lds16(const void* g, void* l) {
  __builtin_amdgcn_global_load_lds(
      (__attribute__((address_space(1))) void*)(g),
      (__attribute__((address_space(3))) void*)(l), 16, 0, 0);
}

__device__ __forceinline__ float clipdiv(float v, float s) {
  v = v / s;
  return fminf(fmaxf(v, -448.f), 448.f);
}

__device__ __forceinline__ u32 pack4_fp8(float a, float b, float c, float d) {
  int w = __builtin_amdgcn_cvt_pk_fp8_f32(a, b, 0, false);
  w = __builtin_amdgcn_cvt_pk_fp8_f32(c, d, w, true);
  return (u32)w;
}

__device__ __forceinline__ v8i rd8(const void* lo, const void* hi) {
  v4i l = *(const v4i*)lo;
  v4i h = *(const v4i*)hi;
  return __builtin_shufflevector(l, h, 0, 1, 2, 3, 4, 5, 6, 7);
}

__device__ __forceinline__ f32x16 mfma32(v8i a, v8i b, f32x16 c) {
  return __builtin_amdgcn_mfma_scale_f32_32x32x64_f8f6f4(
      a, b, c, 0, 0, 0, 0x7f7f7f7f, 0, 0x7f7f7f7f);
}

// ---------- quantize A (row-major M x K, f32 -> e4m3fn) ----------

__global__ __launch_bounds__(256) void quant_a(const float* __restrict__ x,
                                               u32* __restrict__ q,
                                               const float* __restrict__ scale,
                                               int nv4) {
  int base = blockIdx.x * 1024 + threadIdx.x;
  float s = scale[0];
#pragma unroll
  for (int r = 0; r < 4; ++r) {
    int idx = base + r * 256;
    if (idx < nv4) {
      float4 v = ((const float4*)x)[idx];
      q[idx] = pack4_fp8(clipdiv(v.x, s), clipdiv(v.y, s),
                         clipdiv(v.z, s), clipdiv(v.w, s));
    }
  }
}

// ---------- quantize + transpose B (K x N f32 -> N x K fp8), u32-packed ----

__global__ __launch_bounds__(256) void quant_b_t(const float* __restrict__ B,
                                                 uint8_t* __restrict__ qT,
                                                 const float* __restrict__ scale) {
  __shared__ u32 lt[64 * 17];  // 64 n-rows x 16 dwords + 1 pad
  int tid = threadIdx.x;
  int kt = blockIdx.x * 64;
  int nt = blockIdx.y * 64;
  float s = scale[0];

  int kq = tid >> 4;  // 0..15 -> k0 = 4*kq
  int nq = tid & 15;  // 0..15 -> n0 = 4*nq
  int k0 = kq * 4, n0 = nq * 4;
  const float* src = B + (long)(kt + k0) * N_DIM + nt + n0;
  float4 v0 = *(const float4*)(src);
  float4 v1 = *(const float4*)(src + N_DIM);
  float4 v2 = *(const float4*)(src + 2 * N_DIM);
  float4 v3 = *(const float4*)(src + 3 * N_DIM);

  lt[(n0 + 0) * 17 + kq] = pack4_fp8(clipdiv(v0.x, s), clipdiv(v1.x, s),
                                     clipdiv(v2.x, s), clipdiv(v3.x, s));
  lt[(n0 + 1) * 17 + kq] = pack4_fp8(clipdiv(v0.y, s), clipdiv(v1.y, s),
                                     clipdiv(v2.y, s), clipdiv(v3.y, s));
  lt[(n0 + 2) * 17 + kq] = pack4_fp8(clipdiv(v0.z, s), clipdiv(v1.z, s),
                                     clipdiv(v2.z, s), clipdiv(v3.z, s));
  lt[(n0 + 3) * 17 + kq] = pack4_fp8(clipdiv(v0.w, s), clipdiv(v1.w, s),
                                     clipdiv(v2.w, s), clipdiv(v3.w, s));
  __syncthreads();

  int n = tid >> 2, ch = tid & 3;
  uint4 o;
  o.x = lt[n * 17 + ch * 4 + 0];
  o.y = lt[n * 17 + ch * 4 + 1];
  o.z = lt[n * 17 + ch * 4 + 2];
  o.w = lt[n * 17 + ch * 4 + 3];
  *(uint4*)&qT[(long)(nt + n) * K_DIM + kt + ch * 16] = o;
}

// ---------- 256x256 MX-fp8 GEMM, 32x32x64 MFMA, coarse 2-phase ----------
// Identical structure to the round-7 winner (141.7 us, no spill), with the
// MFMA shape switched 16x16x128 -> 32x32x64: half the MFMA instructions
// (16/wave/K-tile), same FLOP, same 24 ds_read_b128 minimum, same acc
// footprint (4x2 frags x 16 = 128), same operand regs. m119 measured the
// 32x32 shape ~15% faster than 16x16 at ubench.
// Fragment layout (f8f6f4 32x32x64): lane holds row/col = lane&31,
// k-bytes (lane>>5)*32 .. +32 per k-step; granule g = ks*4 + (lane>>5)*2 + j,
// swizzled g^(row&7) — uniform 8 lanes/granule (conflict-neutral).
// C/D (m74/m101, shape-determined): col=lane&31, row=(q&3)+8*(q>>2)+4*(lane>>5).

template <int BUF>
__device__ __forceinline__ void stage_tile(const uint8_t* const (&gA)[4],
                                           const uint8_t* const (&gB)[4],
                                           uint8_t* lds, const int (&ldo)[4],
                                           long ko) {
#pragma unroll
  for (int r = 0; r < 4; ++r)
    gload_lds16(gA[r] + ko, lds + BUF * 32768 + ldo[r]);
#pragma unroll
  for (int r = 0; r < 4; ++r)
    gload_lds16(gB[r] + ko, lds + 65536 + BUF * 32768 + ldo[r]);
}

template <int BUF>
__device__ __forceinline__ void compute_tile(const uint8_t* lds,
                                             const int (&offA)[4][4],
                                             const int (&offB)[2][4],
                                             f32x16 (&acc)[4][2]) {
  const uint8_t* Ab = lds + BUF * 32768;
  const uint8_t* Bb = lds + 65536 + BUF * 32768;
#pragma unroll
  for (int ks = 0; ks < 2; ++ks) {
    v8i b[2], a[4];
#pragma unroll
    for (int nj = 0; nj < 2; ++nj)
      b[nj] = rd8(Bb + offB[nj][ks * 2], Bb + offB[nj][ks * 2 + 1]);
#pragma unroll
    for (int mi = 0; mi < 4; ++mi)
      a[mi] = rd8(Ab + offA[mi][ks * 2], Ab + offA[mi][ks * 2 + 1]);
#pragma unroll
    for (int mi = 0; mi < 4; ++mi)
#pragma unroll
      for (int nj = 0; nj < 2; ++nj)
        acc[mi][nj] = mfma32(a[mi], b[nj], acc[mi][nj]);
  }
}

__global__ __launch_bounds__(512, 2) void gemm_mx(const uint8_t* __restrict__ Aq,
                                                  const uint8_t* __restrict__ BqT,
                                                  float* __restrict__ C,
                                                  const float* __restrict__ sA,
                                                  const float* __restrict__ sB) {
  __shared__ __align__(16) uint8_t lds[131072];

  const int tid = threadIdx.x;
  const int lane = tid & 63;
  const int wid = tid >> 6;
  const int wr = wid >> 2;  // 0..1: 128-row strip of A
  const int wc = wid & 3;   // 0..3: 64-col strip of B
  const int l31 = lane & 31;
  const int hi2 = lane >> 5;  // 0..1

  // XCD-aware swizzle: 512 wgs, 64 per XCD chunk (bijective, 512%8==0)
  int bid = blockIdx.x;
  int wg = (bid & 7) * 64 + (bid >> 3);
  const long bm = (long)(wg >> 4) * 256;  // 32 M-tiles
  const long bn = (long)(wg & 15) * 256;  // 16 N-tiles

  // scales: materialize before staging so their loads never sit in the vmem
  // queue during the counted waits.
  float s = sA[0] * sB[0];
  asm volatile("" ::"v"(s));

  // --- staging: 2048 granules per matrix, 4 per thread, pre-swizzled src ---
  const uint8_t* gA[4];
  const uint8_t* gB[4];
  int ldo[4];
#pragma unroll
  for (int r = 0; r < 4; ++r) {
    int gid = tid + 512 * r;
    int row = gid >> 3, gc = gid & 7;
    int sc = (gc ^ (row & 7)) << 4;  // pre-swizzled source granule
    gA[r] = Aq + (bm + row) * (long)K_DIM + sc;
    gB[r] = BqT + (bn + row) * (long)K_DIM + sc;
    ldo[r] = gid * 16;  // linear LDS dest
  }

  // --- fragment read offsets (loop-invariant, swizzled) ---
  int offA[4][4], offB[2][4];
#pragma unroll
  for (int mi = 0; mi < 4; ++mi) {
    int ra = wr * 128 + mi * 32 + l31;  // 0..255
#pragma unroll
    for (int ks = 0; ks < 2; ++ks)
#pragma unroll
      for (int j = 0; j < 2; ++j) {
        int g = ks * 4 + hi2 * 2 + j;
        offA[mi][ks * 2 + j] = ra * 128 + ((g ^ (ra & 7)) << 4);
      }
  }
#pragma unroll
  for (int nj = 0; nj < 2; ++nj) {
    int rb = wc * 64 + nj * 32 + l31;  // 0..255
#pragma unroll
    for (int ks = 0; ks < 2; ++ks)
#pragma unroll
      for (int j = 0; j < 2; ++j) {
        int g = ks * 4 + hi2 * 2 + j;
        offB[nj][ks * 2 + j] = rb * 128 + ((g ^ (rb & 7)) << 4);
      }
  }

  f32x16 acc[4][2] = {};

  // ---- prologue ----
  stage_tile<0>(gA, gB, lds, ldo, 0);
  asm volatile("s_waitcnt vmcnt(0)" ::: "memory");
  __builtin_amdgcn_s_barrier();

  // ---- main loop: 2 K-tiles per iteration, static buffer indices ----
  for (int i = 0; i < NT / 2; ++i) {
    long ko1 = (long)((2 * i + 1) & (NT - 1)) * 128;
    stage_tile<1>(gA, gB, lds, ldo, ko1);   // issue first
    compute_tile<0>(lds, offA, offB, acc);  // 24 reads + 16 MFMA per wave
    asm volatile("s_waitcnt vmcnt(0)" ::: "memory");
    __builtin_amdgcn_s_barrier();

    long ko2 = (long)((2 * i + 2) & (NT - 1)) * 128;  // wraps harmlessly
    stage_tile<0>(gA, gB, lds, ldo, ko2);
    compute_tile<1>(lds, offA, offB, acc);
    asm volatile("s_waitcnt vmcnt(0)" ::: "memory");
    __builtin_amdgcn_s_barrier();
  }

  // ---- epilogue: C-write (32x32 C/D layout) ----
#pragma unroll
  for (int mi = 0; mi < 4; ++mi)
#pragma unroll
    for (int nj = 0; nj < 2; ++nj) {
      f32x16 v = acc[mi][nj];
      long col = bn + wc * 64 + nj * 32 + l31;
#pragma unroll
      for (int q = 0; q < 16; ++q) {
        long row = bm + wr * 128 + mi * 32 + (q & 3) + 8 * (q >> 2) + 4 * hi2;
        C[row * N_DIM + col] = v[q] * s;
      }
    }
}

// ---------- launcher ----------

extern "C" void kernel_launch(void* const* d_in, const int* in_sizes, int n_in,
                              void* d_out, int out_size, void* d_ws, size_t ws_size,
                              hipStream_t stream) {
  const float* A = (const float*)d_in[0];   // (8192, 4096)
  const float* B = (const float*)d_in[1];   // (4096, 4096)
  const float* sA = (const float*)d_in[2];  // input_scale
  const float* sB = (const float*)d_in[4];  // kernel_scale
  float* out = (float*)d_out;

  uint8_t* Aq = (uint8_t*)d_ws;               // M*K fp8
  uint8_t* BqT = Aq + (size_t)M_DIM * K_DIM;  // N*K fp8 (transposed)

  int nv4_a = M_DIM * K_DIM / 4;
  quant_a<<<nv4_a / 1024, 256, 0, stream>>>(A, (u32*)Aq, sA, nv4_a);
  quant_b_t<<<dim3(K_DIM / 64, N_DIM / 64), 256, 0, stream>>>(B, BqT, sB);
  gemm_mx<<<dim3((M_DIM / 256) * (N_DIM / 256)), 512, 0, stream>>>(Aq, BqT, out, sA, sB);
}